// Round 9
// baseline (465.649 us; speedup 1.0000x reference)
//
#include <hip/hip_runtime.h>
#include <hip/hip_bf16.h>

#define T_SEQ   512
#define H_DIM   128
#define N3H     384
#define HSW     128   // h row stride (ushort): 256B rows + 16B-chunk XOR swizzle
#define XS      72    // x row stride (ushort): 144B -> rotation, conflict-free

typedef float f32x4 __attribute__((ext_vector_type(4)));
typedef float f32x2 __attribute__((ext_vector_type(2)));
typedef __bf16 bf16x8 __attribute__((ext_vector_type(8)));
typedef unsigned short us8 __attribute__((ext_vector_type(8)));

static __device__ __forceinline__ unsigned short f2bf(float f) {
    unsigned int u = __builtin_bit_cast(unsigned int, f);
    u += 0x7FFFu + ((u >> 16) & 1u);
    return (unsigned short)(u >> 16);
}

// v_cvt_pk_bf16_f32: lo = bf16(a), hi = bf16(b), RNE (matches f2bf).
static __device__ __forceinline__ unsigned cvt_pk_bf16(float a, float b) {
    unsigned r;
    asm("v_cvt_pk_bf16_f32 %0, %1, %2" : "=v"(r) : "v"(a), "v"(b));
    return r;
}

// LDS-only barrier: lgkmcnt(0), vmcnt untouched -> global prefetch loads
// stay in flight across it.
static __device__ __forceinline__ void lds_barrier() {
    asm volatile("" ::: "memory");
    __builtin_amdgcn_s_waitcnt(0xC07F);
    __builtin_amdgcn_s_barrier();
    asm volatile("" ::: "memory");
}

static __device__ __forceinline__ bf16x8 ld8(const unsigned short* p) {
    return __builtin_bit_cast(bf16x8, *(const us8*)p);
}

static __device__ __forceinline__ f32x2 lo2(f32x4 v) { return (f32x2){ v[0], v[1] }; }
static __device__ __forceinline__ f32x2 hi2(f32x4 v) { return (f32x2){ v[2], v[3] }; }

// 32 blocks x 16 batch rows x 512 threads (8 waves, 2/SIMD).
// Wave w owns N-tiles {w, 8+w, 16+w}: z/r/hh for cols [16w,16w+16) wave-local.
//
// R9 = R6 math (verified 328us: 4-deep rec chains, xw-into-C fold, f32x2
// gates) with ONE scheduling change and no sched directives:
//  - branch-free main loop (last 4 steps peeled, compile-time flags) so a
//    step is a single schedulable region, and
//  - source order rec -> gates_lo -> xw MFMAs -> gates_hi: the independent
//    xw issue sits BETWEEN two VALU chunks, so a wave stalled behind MFMA
//    pipe pressure has VALU to retire (and vice versa) instead of the
//    all-MFMA-then-all-VALU serialization measured through R8.
// R7 (branch-free + SGB pinning) regressed -16%; this round isolates the
// branch-free half without SGB.
__global__ __launch_bounds__(512, 1) void gru_fused(
    const float* __restrict__ inputs, const float* __restrict__ Wx,
    const float* __restrict__ Wh, const float* __restrict__ bias,
    const float* __restrict__ W_state, const float* __restrict__ w1,
    const float* __restrict__ b1, const float* __restrict__ gamma,
    const float* __restrict__ beta, const float* __restrict__ mean,
    const float* __restrict__ var, const float* __restrict__ w2,
    const float* __restrict__ b2, float* __restrict__ out)
{
    __shared__ __attribute__((aligned(16))) unsigned short hb[2][16 * HSW];
    __shared__ __attribute__((aligned(16))) unsigned short xb[2][16 * XS];
    __shared__ float hf[16][H_DIM + 1];

    const int tid  = threadIdx.x;
    const int w    = tid >> 6;      // wave 0..7
    const int lane = tid & 63;
    const int m    = lane & 15;
    const int q    = lane >> 4;
    const int b0   = blockIdx.x * 16;

    const float SCL0 = -1.4426950408889634f;  // -1/ln2  (z,r)
    const float SCL2 =  2.8853900817779268f;  // +2/ln2  (hh)

    // ---- prescaled weight B-fragments in registers for all 512 steps ----
    bf16x8 whB[3][4];
    bf16x8 wxB[3][2];
    f32x4 xinit[3];            // xw-chain C init (biases folded)
    f32x4 rinit2;              // rec-chain C init for hh gate (s2*b_rec)
#pragma unroll
    for (int g = 0; g < 3; ++g) {
        const float s = (g < 2) ? SCL0 : SCL2;
        const int col = (8 * g + w) * 16 + m;   // tile w / 8+w / 16+w
#pragma unroll
        for (int k = 0; k < 4; ++k) {
            us8 tmp;
#pragma unroll
            for (int j = 0; j < 8; ++j) tmp[j] = f2bf(s * Wh[(32 * k + 8 * q + j) * N3H + col]);
            whB[g][k] = __builtin_bit_cast(bf16x8, tmp);
        }
#pragma unroll
        for (int k = 0; k < 2; ++k) {
            us8 tmp;
#pragma unroll
            for (int j = 0; j < 8; ++j) tmp[j] = f2bf(s * Wx[(32 * k + 8 * q + j) * N3H + col]);
            wxB[g][k] = __builtin_bit_cast(bf16x8, tmp);
        }
        const float bi = s * bias[col];
        const float br = s * bias[N3H + col];
        if (g < 2) {
            const float bc = bi + br;     // z,r: both biases into xw chain
            xinit[g] = (f32x4){ bc, bc, bc, bc };
        } else {
            xinit[g] = (f32x4){ bi, bi, bi, bi };
            rinit2   = (f32x4){ br, br, br, br };  // r multiplies this part
        }
    }

    // loop-invariant LDS offsets (ushort units), XOR-swizzled h layout:
    // logical 16B-chunk c of row r lives at physical chunk c^(r&7).
    int hro[4], hwo[4], xro[2];
#pragma unroll
    for (int k = 0; k < 4; ++k) hro[k] = m * HSW + (((4 * k + q) ^ (m & 7)) * 8);
#pragma unroll
    for (int i = 0; i < 4; ++i) {
        const int row = 4 * q + i;
        hwo[i] = row * HSW + (((2 * w + (m >> 3)) ^ (row & 7)) * 8) + (m & 7);
    }
#pragma unroll
    for (int k = 0; k < 2; ++k) xro[k] = m * XS + 32 * k + 8 * q;

    // staging: ALL 512 threads, 2 consecutive floats each
    const int sr = tid >> 5;                 // batch row 0..15
    const int c2 = (tid & 31) * 2;           // col 0..62
    const int xwoff = sr * XS + c2;
    const float* xs = inputs + ((size_t)(b0 + sr) * T_SEQ) * 65 + c2;

    // zero h(0)
    {
        unsigned int* p = (unsigned int*)hb[0];
        for (int i = tid; i < 16 * HSW / 2; i += 512) p[i] = 0;
    }
    // stage x(0), x(1)
    *(unsigned*)&xb[0][xwoff] = cvt_pk_bf16(xs[0], xs[1]);
    *(unsigned*)&xb[1][xwoff] = cvt_pk_bf16(xs[65], xs[66]);
    lds_barrier();

    // xw(0)
    f32x4 xwA[3], xwB[3];
    {
        bf16x8 xa[2];
#pragma unroll
        for (int k = 0; k < 2; ++k) xa[k] = ld8(&xb[0][xro[k]]);
#pragma unroll
        for (int g = 0; g < 3; ++g) {
            f32x4 acc = __builtin_amdgcn_mfma_f32_16x16x32_bf16(xa[0], wxB[g][0], xinit[g], 0, 0, 0);
            acc = __builtin_amdgcn_mfma_f32_16x16x32_bf16(xa[1], wxB[g][1], acc, 0, 0, 0);
            xwA[g] = acc;
        }
    }

    float pf0a = xs[2 * 65], pf0b = xs[2 * 65 + 1];   // x(2)
    float pf1a = 0.f, pf1b = 0.f;

    const float* pf_ptr = xs + 3 * 65;   // next prefetch target x(t+3)

    f32x2 hreg_lo = { 0.f, 0.f }, hreg_hi = { 0.f, 0.f };

    // one packed gate pair (native vector ops). az',ar' complete pre-acts;
    // rc2 = s2*(rec_h+br); xw2 = s2*(xh+bi); hold = previous h pair.
    auto gate_pair = [&](f32x2 az, f32x2 ar, f32x2 rc2, f32x2 xw2,
                         f32x2 hold) -> f32x2 {
        f32x2 ea, eb;
        ea[0] = __builtin_amdgcn_exp2f(az[0]); ea[1] = __builtin_amdgcn_exp2f(az[1]);
        eb[0] = __builtin_amdgcn_exp2f(ar[0]); eb[1] = __builtin_amdgcn_exp2f(ar[1]);
        const f32x2 Pa = ea + 1.0f;
        const f32x2 Pb = eb + 1.0f;
        const f32x2 PP = Pa * Pb;
        f32x2 D;
        D[0] = __builtin_amdgcn_rcpf(PP[0]); D[1] = __builtin_amdgcn_rcpf(PP[1]);
        const f32x2 z = Pb * D;      // 1/Pa
        const f32x2 r = Pa * D;      // 1/Pb
        const f32x2 u = __builtin_elementwise_fma(r, rc2, xw2);
        f32x2 ec;
        ec[0] = __builtin_amdgcn_exp2f(u[0]); ec[1] = __builtin_amdgcn_exp2f(u[1]);
        const f32x2 Pc = ec + 1.0f;
        f32x2 rv;
        rv[0] = __builtin_amdgcn_rcpf(Pc[0]); rv[1] = __builtin_amdgcn_rcpf(Pc[1]);
        const f32x2 hh = __builtin_elementwise_fma((f32x2){ -2.f, -2.f }, rv,
                                                   (f32x2){ 1.f, 1.f });
        const f32x2 df = hold - hh;
        return __builtin_elementwise_fma(z, df, hh);   // z*(hold-hh) + hh
    };

    // do_pf/do_xw/do_stage are compile-time literals at every call site;
    // main-loop instantiation is a single branch-free scheduling region.
    auto step = [&](f32x4* xw_cur, f32x4* xw_next,
                    float& pfLa, float& pfLb, float pfUa, float pfUb,
                    const unsigned short* hcur, unsigned short* hnxt,
                    const unsigned short* xnxt, unsigned short* xwr,
                    bool do_pf, bool do_xw, bool do_stage) {
        // global prefetch x(t+3) — spans the barrier (vmcnt not drained)
        if (do_pf) { pfLa = pf_ptr[0]; pfLb = pf_ptr[1]; pf_ptr += 65; }

        lds_barrier();

        // issue all LDS reads up front (h fragments + next-step x fragments)
        bf16x8 ha[4];
#pragma unroll
        for (int k = 0; k < 4; ++k) ha[k] = ld8(&hcur[hro[k]]);
        bf16x8 xa[2];
        if (do_xw) {
#pragma unroll
            for (int k = 0; k < 2; ++k) xa[k] = ld8(&xnxt[xro[k]]);
        }

        // rec(t) = h(t) @ Wh' — 4-deep chain per gate.  z,r chains start
        // from xw_cur[g]: the xw+rec add happens in the matrix pipe.
        f32x4 racc[3];
#pragma unroll
        for (int g = 0; g < 3; ++g) {
            f32x4 acc = __builtin_amdgcn_mfma_f32_16x16x32_bf16(ha[0], whB[g][0], (g == 2) ? rinit2 : xw_cur[g], 0, 0, 0);
            acc = __builtin_amdgcn_mfma_f32_16x16x32_bf16(ha[1], whB[g][1], acc, 0, 0, 0);
            acc = __builtin_amdgcn_mfma_f32_16x16x32_bf16(ha[2], whB[g][2], acc, 0, 0, 0);
            acc = __builtin_amdgcn_mfma_f32_16x16x32_bf16(ha[3], whB[g][3], acc, 0, 0, 0);
            racc[g] = acc;
        }

        // gates lo pair + its h-write: first VALU chunk
        const f32x2 hn_lo = gate_pair(lo2(racc[0]), lo2(racc[1]),
                                      lo2(racc[2]), lo2(xw_cur[2]), hreg_lo);
        hreg_lo = hn_lo;
        {
            const unsigned p01 = cvt_pk_bf16(hn_lo[0], hn_lo[1]);
            hnxt[hwo[0]] = (unsigned short)(p01);
            hnxt[hwo[1]] = (unsigned short)(p01 >> 16);
        }

        // xw(t+1) — independent MFMA work, issued between the two gate
        // VALU chunks so pipe time hides under VALU (and vice versa)
        if (do_xw) {
#pragma unroll
            for (int g = 0; g < 3; ++g) {
                f32x4 acc = __builtin_amdgcn_mfma_f32_16x16x32_bf16(xa[0], wxB[g][0], xinit[g], 0, 0, 0);
                acc = __builtin_amdgcn_mfma_f32_16x16x32_bf16(xa[1], wxB[g][1], acc, 0, 0, 0);
                xw_next[g] = acc;
            }
        }

        // gates hi pair + its h-write: second VALU chunk
        const f32x2 hn_hi = gate_pair(hi2(racc[0]), hi2(racc[1]),
                                      hi2(racc[2]), hi2(xw_cur[2]), hreg_hi);
        hreg_hi = hn_hi;
        {
            const unsigned p23 = cvt_pk_bf16(hn_hi[0], hn_hi[1]);
            hnxt[hwo[2]] = (unsigned short)(p23);
            hnxt[hwo[3]] = (unsigned short)(p23 >> 16);
        }

        // stage x(t+2) into LDS at end of step (off the h critical path)
        if (do_stage) *(unsigned*)&xwr[xwoff] = cvt_pk_bf16(pfUa, pfUb);
    };

    // main loop: t = 0..507, all flags true -> branch-free region
    for (int it = 0; it < 254; ++it) {
        step(xwA, xwB, pf1a, pf1b, pf0a, pf0b, hb[0], hb[1], xb[1], xb[0],
             true, true, true);
        step(xwB, xwA, pf0a, pf0b, pf1a, pf1b, hb[1], hb[0], xb[0], xb[1],
             true, true, true);
    }
    // epilogue: t = 508..511 (tail conditions peeled; verified in R7)
    step(xwA, xwB, pf1a, pf1b, pf0a, pf0b, hb[0], hb[1], xb[1], xb[0],
         true,  true,  true);    // t=508
    step(xwB, xwA, pf0a, pf0b, pf1a, pf1b, hb[1], hb[0], xb[0], xb[1],
         false, true,  true);    // t=509
    step(xwA, xwB, pf1a, pf1b, pf0a, pf0b, hb[0], hb[1], xb[1], xb[0],
         false, true,  false);   // t=510
    step(xwB, xwA, pf0a, pf0b, pf1a, pf1b, hb[1], hb[0], xb[0], xb[1],
         false, false, false);   // t=511

    // ---- fused tail: +W_state, w1/ReLU/BN, w2 ----
    hf[4 * q + 0][16 * w + m] = hreg_lo[0];
    hf[4 * q + 1][16 * w + m] = hreg_lo[1];
    hf[4 * q + 2][16 * w + m] = hreg_hi[0];
    hf[4 * q + 3][16 * w + m] = hreg_hi[1];
    __syncthreads();

    {
        const int row = tid >> 5;
        const int c0  = (tid & 31) * 4;
        const float sf = inputs[((size_t)(b0 + row) * T_SEQ + (T_SEQ - 1)) * 65 + 64];
        int si = (int)sf;
        si = si < 0 ? 0 : (si > 2 ? 2 : si);
#pragma unroll
        for (int c = 0; c < 4; ++c)
            hf[row][c0 + c] += W_state[si * H_DIM + c0 + c];
    }
    __syncthreads();

    {
        const int row = tid >> 5;
        const int jj  = (tid & 31) * 2;
        f32x2 acc = { b1[jj], b1[jj + 1] };
        for (int k = 0; k < H_DIM; ++k) {
            const float hv = hf[row][k];
            const f32x2 wv = *(const f32x2*)(w1 + k * 64 + jj);
            acc[0] = fmaf(hv, wv[0], acc[0]);
            acc[1] = fmaf(hv, wv[1], acc[1]);
        }
        float v = 0.0f;
#pragma unroll
        for (int ii = 0; ii < 2; ++ii) {
            const int j = jj + ii;
            float a = fmaxf(acc[ii], 0.0f);
            a = (a - mean[j]) * rsqrtf(var[j] + 1e-3f) * gamma[j] + beta[j];
            v = fmaf(a, w2[j], v);
        }
        v += __shfl_down(v, 16);
        v += __shfl_down(v, 8);
        v += __shfl_down(v, 4);
        v += __shfl_down(v, 2);
        v += __shfl_down(v, 1);
        if ((tid & 31) == 0) out[b0 + row] = v + b2[0];
    }
}

extern "C" void kernel_launch(void* const* d_in, const int* in_sizes, int n_in,
                              void* d_out, int out_size, void* d_ws, size_t ws_size,
                              hipStream_t stream) {
    (void)in_sizes; (void)n_in; (void)out_size; (void)d_ws; (void)ws_size;
    const float* inputs  = (const float*)d_in[0];
    const float* Wx      = (const float*)d_in[1];
    const float* Wh      = (const float*)d_in[2];
    const float* bias    = (const float*)d_in[3];
    const float* W_state = (const float*)d_in[4];
    const float* w1      = (const float*)d_in[5];
    const float* b1      = (const float*)d_in[6];
    const float* gamma   = (const float*)d_in[7];
    const float* beta    = (const float*)d_in[8];
    const float* mean    = (const float*)d_in[9];
    const float* var     = (const float*)d_in[10];
    const float* w2      = (const float*)d_in[11];
    const float* b2      = (const float*)d_in[12];
    float* out = (float*)d_out;

    gru_fused<<<32, 512, 0, stream>>>(inputs, Wx, Wh, bias, W_state, w1, b1,
                                      gamma, beta, mean, var, w2, b2, out);
}

// Round 10
// 410.143 us; speedup vs baseline: 1.1353x; 1.1353x over previous
//
#include <hip/hip_runtime.h>
#include <hip/hip_bf16.h>

#define T_SEQ   512
#define H_DIM   128
#define N3H     384
#define HSW     128   // h row stride (ushort): 256B rows + 16B-chunk XOR swizzle
#define XS      72    // x row stride (ushort): 144B -> rotation, conflict-free

typedef float f32x4 __attribute__((ext_vector_type(4)));
typedef float f32x2 __attribute__((ext_vector_type(2)));
typedef __bf16 bf16x8 __attribute__((ext_vector_type(8)));
typedef unsigned short us8 __attribute__((ext_vector_type(8)));

static __device__ __forceinline__ unsigned short f2bf(float f) {
    unsigned int u = __builtin_bit_cast(unsigned int, f);
    u += 0x7FFFu + ((u >> 16) & 1u);
    return (unsigned short)(u >> 16);
}

// v_cvt_pk_bf16_f32: lo = bf16(a), hi = bf16(b), RNE (matches f2bf).
static __device__ __forceinline__ unsigned cvt_pk_bf16(float a, float b) {
    unsigned r;
    asm("v_cvt_pk_bf16_f32 %0, %1, %2" : "=v"(r) : "v"(a), "v"(b));
    return r;
}

// LDS-only barrier: lgkmcnt(0), vmcnt untouched -> global prefetch loads
// stay in flight across it.
static __device__ __forceinline__ void lds_barrier() {
    asm volatile("" ::: "memory");
    __builtin_amdgcn_s_waitcnt(0xC07F);
    __builtin_amdgcn_s_barrier();
    asm volatile("" ::: "memory");
}

static __device__ __forceinline__ bf16x8 ld8(const unsigned short* p) {
    return __builtin_bit_cast(bf16x8, *(const us8*)p);
}

static __device__ __forceinline__ f32x2 lo2(f32x4 v) { return (f32x2){ v[0], v[1] }; }
static __device__ __forceinline__ f32x2 hi2(f32x4 v) { return (f32x2){ v[2], v[3] }; }

// 32 blocks x 16 batch rows x 512 threads (8 waves, 2/SIMD).
// Wave w owns N-tiles {w, 8+w, 16+w}: z/r/hh for cols [16w,16w+16) wave-local.
//
// R10 = exact revert to the verified R6 kernel (328 us), the best-known
// state.  Scheduling arc concluded: setprio stagger (R4), SGB pinning (R7),
// rec chain split (R8), and branch-free reorder (R9) ALL regressed or were
// null vs this form -- the compiler's natural schedule of this branchy body
// is the local optimum.  Structural floors per SIMD/step: MFMA ~576 cyc
// (36 x 16, fixed work), VALU+trans ~670 (trans floor 320 algorithmic),
// latency/barrier ~290 (minimum for the per-step h-exchange).
// Pre-activations PRE-SCALED: z,r rows by -1/ln2 (sigmoid = 1/(1+exp2)),
// hh rows by +2/ln2 (tanh(u) = 1 - 2/(1+exp2(u'))).
__global__ __launch_bounds__(512, 1) void gru_fused(
    const float* __restrict__ inputs, const float* __restrict__ Wx,
    const float* __restrict__ Wh, const float* __restrict__ bias,
    const float* __restrict__ W_state, const float* __restrict__ w1,
    const float* __restrict__ b1, const float* __restrict__ gamma,
    const float* __restrict__ beta, const float* __restrict__ mean,
    const float* __restrict__ var, const float* __restrict__ w2,
    const float* __restrict__ b2, float* __restrict__ out)
{
    __shared__ __attribute__((aligned(16))) unsigned short hb[2][16 * HSW];
    __shared__ __attribute__((aligned(16))) unsigned short xb[2][16 * XS];
    __shared__ float hf[16][H_DIM + 1];

    const int tid  = threadIdx.x;
    const int w    = tid >> 6;      // wave 0..7
    const int lane = tid & 63;
    const int m    = lane & 15;
    const int q    = lane >> 4;
    const int b0   = blockIdx.x * 16;

    const float SCL0 = -1.4426950408889634f;  // -1/ln2  (z,r)
    const float SCL2 =  2.8853900817779268f;  // +2/ln2  (hh)

    // ---- prescaled weight B-fragments in registers for all 512 steps ----
    bf16x8 whB[3][4];
    bf16x8 wxB[3][2];
    f32x4 xinit[3];            // xw-chain C init (biases folded)
    f32x4 rinit2;              // rec-chain C init for hh gate (s2*b_rec)
#pragma unroll
    for (int g = 0; g < 3; ++g) {
        const float s = (g < 2) ? SCL0 : SCL2;
        const int col = (8 * g + w) * 16 + m;   // tile w / 8+w / 16+w
#pragma unroll
        for (int k = 0; k < 4; ++k) {
            us8 tmp;
#pragma unroll
            for (int j = 0; j < 8; ++j) tmp[j] = f2bf(s * Wh[(32 * k + 8 * q + j) * N3H + col]);
            whB[g][k] = __builtin_bit_cast(bf16x8, tmp);
        }
#pragma unroll
        for (int k = 0; k < 2; ++k) {
            us8 tmp;
#pragma unroll
            for (int j = 0; j < 8; ++j) tmp[j] = f2bf(s * Wx[(32 * k + 8 * q + j) * N3H + col]);
            wxB[g][k] = __builtin_bit_cast(bf16x8, tmp);
        }
        const float bi = s * bias[col];
        const float br = s * bias[N3H + col];
        if (g < 2) {
            const float bc = bi + br;     // z,r: both biases into xw chain
            xinit[g] = (f32x4){ bc, bc, bc, bc };
        } else {
            xinit[g] = (f32x4){ bi, bi, bi, bi };
            rinit2   = (f32x4){ br, br, br, br };  // r multiplies this part
        }
    }

    // loop-invariant LDS offsets (ushort units), XOR-swizzled h layout:
    // logical 16B-chunk c of row r lives at physical chunk c^(r&7).
    int hro[4], hwo[4], xro[2];
#pragma unroll
    for (int k = 0; k < 4; ++k) hro[k] = m * HSW + (((4 * k + q) ^ (m & 7)) * 8);
#pragma unroll
    for (int i = 0; i < 4; ++i) {
        const int row = 4 * q + i;
        hwo[i] = row * HSW + (((2 * w + (m >> 3)) ^ (row & 7)) * 8) + (m & 7);
    }
#pragma unroll
    for (int k = 0; k < 2; ++k) xro[k] = m * XS + 32 * k + 8 * q;

    // staging: ALL 512 threads, 2 consecutive floats each
    const int sr = tid >> 5;                 // batch row 0..15
    const int c2 = (tid & 31) * 2;           // col 0..62
    const int xwoff = sr * XS + c2;
    const float* xs = inputs + ((size_t)(b0 + sr) * T_SEQ) * 65 + c2;

    // zero h(0)
    {
        unsigned int* p = (unsigned int*)hb[0];
        for (int i = tid; i < 16 * HSW / 2; i += 512) p[i] = 0;
    }
    // stage x(0), x(1)
    *(unsigned*)&xb[0][xwoff] = cvt_pk_bf16(xs[0], xs[1]);
    *(unsigned*)&xb[1][xwoff] = cvt_pk_bf16(xs[65], xs[66]);
    lds_barrier();

    // xw(0)
    f32x4 xwA[3], xwB[3];
    {
        bf16x8 xa[2];
#pragma unroll
        for (int k = 0; k < 2; ++k) xa[k] = ld8(&xb[0][xro[k]]);
#pragma unroll
        for (int g = 0; g < 3; ++g) {
            f32x4 acc = __builtin_amdgcn_mfma_f32_16x16x32_bf16(xa[0], wxB[g][0], xinit[g], 0, 0, 0);
            acc = __builtin_amdgcn_mfma_f32_16x16x32_bf16(xa[1], wxB[g][1], acc, 0, 0, 0);
            xwA[g] = acc;
        }
    }

    float pf0a = xs[2 * 65], pf0b = xs[2 * 65 + 1];   // x(2)
    float pf1a = 0.f, pf1b = 0.f;

    f32x2 hreg_lo = { 0.f, 0.f }, hreg_hi = { 0.f, 0.f };

    // one packed gate pair (native vector ops; compiler picks lowering).
    // az',ar' complete pre-acts; rc2 = s2*(rec_h+br); xw2 = s2*(xh+bi);
    // hold = previous h pair.  Returns new h pair.
    auto gate_pair = [&](f32x2 az, f32x2 ar, f32x2 rc2, f32x2 xw2,
                         f32x2 hold) -> f32x2 {
        f32x2 ea, eb;
        ea[0] = __builtin_amdgcn_exp2f(az[0]); ea[1] = __builtin_amdgcn_exp2f(az[1]);
        eb[0] = __builtin_amdgcn_exp2f(ar[0]); eb[1] = __builtin_amdgcn_exp2f(ar[1]);
        const f32x2 Pa = ea + 1.0f;
        const f32x2 Pb = eb + 1.0f;
        const f32x2 PP = Pa * Pb;
        f32x2 D;
        D[0] = __builtin_amdgcn_rcpf(PP[0]); D[1] = __builtin_amdgcn_rcpf(PP[1]);
        const f32x2 z = Pb * D;      // 1/Pa
        const f32x2 r = Pa * D;      // 1/Pb
        const f32x2 u = __builtin_elementwise_fma(r, rc2, xw2);
        f32x2 ec;
        ec[0] = __builtin_amdgcn_exp2f(u[0]); ec[1] = __builtin_amdgcn_exp2f(u[1]);
        const f32x2 Pc = ec + 1.0f;
        f32x2 rv;
        rv[0] = __builtin_amdgcn_rcpf(Pc[0]); rv[1] = __builtin_amdgcn_rcpf(Pc[1]);
        const f32x2 hh = __builtin_elementwise_fma((f32x2){ -2.f, -2.f }, rv,
                                                   (f32x2){ 1.f, 1.f });
        const f32x2 df = hold - hh;
        return __builtin_elementwise_fma(z, df, hh);   // z*(hold-hh) + hh
    };

    auto step = [&](int t, f32x4* xw_cur, f32x4* xw_next,
                    float& pfLa, float& pfLb, float pfUa, float pfUb,
                    const unsigned short* hcur, unsigned short* hnxt,
                    const unsigned short* xnxt, unsigned short* xwr) {
        // global prefetch x(t+3) — spans the barrier (vmcnt not drained)
        if (t <= T_SEQ - 4) { pfLa = xs[(t + 3) * 65]; pfLb = xs[(t + 3) * 65 + 1]; }

        lds_barrier();

        // issue all LDS reads up front (h fragments + next-step x fragments)
        bf16x8 ha[4];
#pragma unroll
        for (int k = 0; k < 4; ++k) ha[k] = ld8(&hcur[hro[k]]);
        bf16x8 xa[2];
        if (t < T_SEQ - 1) {
#pragma unroll
            for (int k = 0; k < 2; ++k) xa[k] = ld8(&xnxt[xro[k]]);
        }

        // rec(t) = h(t) @ Wh' — 4-deep chain per gate.  z,r chains start
        // from xw_cur[g]: the xw+rec add happens in the matrix pipe.
        f32x4 racc[3];
#pragma unroll
        for (int g = 0; g < 3; ++g) {
            f32x4 acc = __builtin_amdgcn_mfma_f32_16x16x32_bf16(ha[0], whB[g][0], (g == 2) ? rinit2 : xw_cur[g], 0, 0, 0);
            acc = __builtin_amdgcn_mfma_f32_16x16x32_bf16(ha[1], whB[g][1], acc, 0, 0, 0);
            acc = __builtin_amdgcn_mfma_f32_16x16x32_bf16(ha[2], whB[g][2], acc, 0, 0, 0);
            acc = __builtin_amdgcn_mfma_f32_16x16x32_bf16(ha[3], whB[g][3], acc, 0, 0, 0);
            racc[g] = acc;
        }

        // xw(t+1) — independent; issued before the gate block so the
        // transcendental burst overlaps its pipe drain
        if (t < T_SEQ - 1) {
#pragma unroll
            for (int g = 0; g < 3; ++g) {
                f32x4 acc = __builtin_amdgcn_mfma_f32_16x16x32_bf16(xa[0], wxB[g][0], xinit[g], 0, 0, 0);
                acc = __builtin_amdgcn_mfma_f32_16x16x32_bf16(xa[1], wxB[g][1], acc, 0, 0, 0);
                xw_next[g] = acc;
            }
        }

        // gates on two element-pairs
        const f32x2 hn_lo = gate_pair(lo2(racc[0]), lo2(racc[1]),
                                      lo2(racc[2]), lo2(xw_cur[2]), hreg_lo);
        const f32x2 hn_hi = gate_pair(hi2(racc[0]), hi2(racc[1]),
                                      hi2(racc[2]), hi2(xw_cur[2]), hreg_hi);
        hreg_lo = hn_lo;
        hreg_hi = hn_hi;

        // write h(t+1) (swizzled scatter) via packed bf16 convert
        {
            const unsigned p01 = cvt_pk_bf16(hn_lo[0], hn_lo[1]);
            const unsigned p23 = cvt_pk_bf16(hn_hi[0], hn_hi[1]);
            hnxt[hwo[0]] = (unsigned short)(p01);
            hnxt[hwo[1]] = (unsigned short)(p01 >> 16);
            hnxt[hwo[2]] = (unsigned short)(p23);
            hnxt[hwo[3]] = (unsigned short)(p23 >> 16);
        }

        // stage x(t+2) into LDS at end of step (off the h critical path)
        if (t <= T_SEQ - 3) *(unsigned*)&xwr[xwoff] = cvt_pk_bf16(pfUa, pfUb);
    };

    for (int t = 0; t < T_SEQ; t += 2) {
        step(t,     xwA, xwB, pf1a, pf1b, pf0a, pf0b, hb[0], hb[1], xb[1], xb[0]);
        step(t + 1, xwB, xwA, pf0a, pf0b, pf1a, pf1b, hb[1], hb[0], xb[0], xb[1]);
    }

    // ---- fused tail: +W_state, w1/ReLU/BN, w2 ----
    hf[4 * q + 0][16 * w + m] = hreg_lo[0];
    hf[4 * q + 1][16 * w + m] = hreg_lo[1];
    hf[4 * q + 2][16 * w + m] = hreg_hi[0];
    hf[4 * q + 3][16 * w + m] = hreg_hi[1];
    __syncthreads();

    {
        const int row = tid >> 5;
        const int c0  = (tid & 31) * 4;
        const float sf = inputs[((size_t)(b0 + row) * T_SEQ + (T_SEQ - 1)) * 65 + 64];
        int si = (int)sf;
        si = si < 0 ? 0 : (si > 2 ? 2 : si);
#pragma unroll
        for (int c = 0; c < 4; ++c)
            hf[row][c0 + c] += W_state[si * H_DIM + c0 + c];
    }
    __syncthreads();

    {
        const int row = tid >> 5;
        const int jj  = (tid & 31) * 2;
        f32x2 acc = { b1[jj], b1[jj + 1] };
        for (int k = 0; k < H_DIM; ++k) {
            const float hv = hf[row][k];
            const f32x2 wv = *(const f32x2*)(w1 + k * 64 + jj);
            acc[0] = fmaf(hv, wv[0], acc[0]);
            acc[1] = fmaf(hv, wv[1], acc[1]);
        }
        float v = 0.0f;
#pragma unroll
        for (int ii = 0; ii < 2; ++ii) {
            const int j = jj + ii;
            float a = fmaxf(acc[ii], 0.0f);
            a = (a - mean[j]) * rsqrtf(var[j] + 1e-3f) * gamma[j] + beta[j];
            v = fmaf(a, w2[j], v);
        }
        v += __shfl_down(v, 16);
        v += __shfl_down(v, 8);
        v += __shfl_down(v, 4);
        v += __shfl_down(v, 2);
        v += __shfl_down(v, 1);
        if ((tid & 31) == 0) out[b0 + row] = v + b2[0];
    }
}

extern "C" void kernel_launch(void* const* d_in, const int* in_sizes, int n_in,
                              void* d_out, int out_size, void* d_ws, size_t ws_size,
                              hipStream_t stream) {
    (void)in_sizes; (void)n_in; (void)out_size; (void)d_ws; (void)ws_size;
    const float* inputs  = (const float*)d_in[0];
    const float* Wx      = (const float*)d_in[1];
    const float* Wh      = (const float*)d_in[2];
    const float* bias    = (const float*)d_in[3];
    const float* W_state = (const float*)d_in[4];
    const float* w1      = (const float*)d_in[5];
    const float* b1      = (const float*)d_in[6];
    const float* gamma   = (const float*)d_in[7];
    const float* beta    = (const float*)d_in[8];
    const float* mean    = (const float*)d_in[9];
    const float* var     = (const float*)d_in[10];
    const float* w2      = (const float*)d_in[11];
    const float* b2      = (const float*)d_in[12];
    float* out = (float*)d_out;

    gru_fused<<<32, 512, 0, stream>>>(inputs, Wx, Wh, bias, W_state, w1, b1,
                                      gamma, beta, mean, var, w2, b2, out);
}